// Round 2
// baseline (1689.319 us; speedup 1.0000x reference)
//
#include <hip/hip_runtime.h>

#define BB 8
#define LQ 4096
#define LK 32768
#define DD 64
#define UU 8000
#define NU 45
#define NPH 16
#define KT5 1024
#define NT5 32

__device__ __forceinline__ unsigned int fkey(float v){
  unsigned int u = __float_as_uint(v);
  return (u & 0x80000000u) ? ~u : (u | 0x80000000u);
}

// ---------------- Stage 1: M[b,q] = max_u(q.K_samp[u]) - sum_u(q.K_samp[u])/8000 ----------------
// lane = q row; u-phase = blockIdx.x so the K row pointer is block-uniform (scalar-load friendly).
// Partials per phase, combined in k_select.
__global__ __launch_bounds__(64) void k_M(const float* __restrict__ q,
                                          const float* __restrict__ Kg,
                                          const int* __restrict__ idx,
                                          float* __restrict__ Mpmax, float* __restrict__ Mpsum){
  const int ph = blockIdx.x, qt = blockIdx.y, b = blockIdx.z;
  const int lane = threadIdx.x;
  const int qrow = qt*64 + lane;
  const float* qp = q + ((size_t)(b*LQ + qrow))*DD;
  float qv[64];
  #pragma unroll
  for (int j=0;j<16;j++){
    float4 t = ((const float4*)qp)[j];
    qv[4*j]=t.x; qv[4*j+1]=t.y; qv[4*j+2]=t.z; qv[4*j+3]=t.w;
  }
  float vmax = -INFINITY, vsum = 0.0f;
  for (int u = ph; u < UU; u += NPH){
    const float* kp = Kg + ((size_t)(b*LK + idx[u]))*DD;   // block-uniform address
    float a0=0.f,a1=0.f,a2=0.f,a3=0.f;
    #pragma unroll
    for (int j=0;j<64;j+=4){
      a0 = fmaf(qv[j],   kp[j],   a0);
      a1 = fmaf(qv[j+1], kp[j+1], a1);
      a2 = fmaf(qv[j+2], kp[j+2], a2);
      a3 = fmaf(qv[j+3], kp[j+3], a3);
    }
    float s = (a0+a1)+(a2+a3);
    vmax = fmaxf(vmax, s);
    vsum += s;
  }
  size_t o = ((size_t)(b*LQ + qrow))*NPH + ph;
  Mpmax[o] = vmax; Mpsum[o] = vsum;
}

// ---------------- Stage 2: per-batch stable bottom-45 of M (matches jax.lax.top_k(-M, 45)) ------
__global__ __launch_bounds__(256) void k_select(const float* __restrict__ Mpmax, const float* __restrict__ Mpsum,
                                                const float* __restrict__ q,
                                                int* __restrict__ MtopG, float* __restrict__ Qred){
  const int b = blockIdx.x, tid = threadIdx.x;
  __shared__ float Mv[LQ];
  __shared__ unsigned long long red[256];
  __shared__ int mtop[NU];
  for (int qq = tid; qq < LQ; qq += 256){
    size_t base = ((size_t)(b*LQ + qq))*NPH;
    float mx = -INFINITY, sm = 0.0f;
    #pragma unroll
    for (int p=0;p<NPH;p++){ mx = fmaxf(mx, Mpmax[base+p]); sm += Mpsum[base+p]; }
    Mv[qq] = mx - sm / 8000.0f;
  }
  __syncthreads();
  for (int i=0;i<NU;i++){
    unsigned long long best = ~0ull;
    for (int qq = tid; qq < LQ; qq += 256){
      unsigned long long kk = (((unsigned long long)fkey(Mv[qq]))<<32) | (unsigned int)qq;
      if (kk < best) best = kk;
    }
    red[tid] = best; __syncthreads();
    for (int s=128; s>0; s>>=1){
      if (tid < s && red[tid+s] < red[tid]) red[tid] = red[tid+s];
      __syncthreads();
    }
    int sel = (int)(red[0] & 0xFFFFFFFFull);
    __syncthreads();
    if (tid == 0){ Mv[sel] = INFINITY; mtop[i] = sel; }
    __syncthreads();
  }
  if (tid < NU) MtopG[b*NU + tid] = mtop[tid];
  for (int e = tid; e < NU*DD; e += 256){
    int ui = e >> 6, d = e & 63;
    Qred[((size_t)(b*NU + ui))*DD + d] = q[((size_t)(b*LQ + mtop[ui]))*DD + d];
  }
}

// ---------------- Stage 3: attn_scores (pre-softmax) -> output 1 --------------------------------
__global__ __launch_bounds__(256) void k_scores(const float* __restrict__ Kg,
                                                const float* __restrict__ Qred,
                                                float* __restrict__ out1){
  const int b = blockIdx.y;
  const int k = blockIdx.x*256 + threadIdx.x;
  const float* kp = Kg + ((size_t)(b*LK + k))*DD;
  float kv[64];
  #pragma unroll
  for (int j=0;j<16;j++){
    float4 t = ((const float4*)kp)[j];
    kv[4*j]=t.x; kv[4*j+1]=t.y; kv[4*j+2]=t.z; kv[4*j+3]=t.w;
  }
  for (int u=0; u<NU; u++){
    const float* qr = Qred + ((size_t)(b*NU+u))*DD;   // block-uniform -> scalar loads
    float a0=0.f,a1=0.f,a2=0.f,a3=0.f;
    #pragma unroll
    for (int j=0;j<64;j+=4){
      a0 = fmaf(kv[j],   qr[j],   a0);
      a1 = fmaf(kv[j+1], qr[j+1], a1);
      a2 = fmaf(kv[j+2], qr[j+2], a2);
      a3 = fmaf(kv[j+3], qr[j+3], a3);
    }
    float s = ((a0+a1)+(a2+a3))*0.125f;
    out1[((size_t)(b*NU+u)<<15) + k] = s;
  }
}

// ---------------- Stage 4a: softmax row stats ----------------------------------------------------
__global__ __launch_bounds__(256) void k_rowstats(const float* __restrict__ out1,
                                                  float* __restrict__ rowm, float* __restrict__ rowinvl){
  const int r = blockIdx.x, tid = threadIdx.x;
  const float* row = out1 + ((size_t)r << 15);
  __shared__ float red[256];
  float mx = -INFINITY;
  for (int k = tid; k < LK; k += 256) mx = fmaxf(mx, row[k]);
  red[tid] = mx; __syncthreads();
  for (int s=128;s>0;s>>=1){ if (tid<s) red[tid] = fmaxf(red[tid], red[tid+s]); __syncthreads(); }
  float m = red[0]; __syncthreads();
  float sm = 0.0f;
  for (int k = tid; k < LK; k += 256) sm += __expf(row[k] - m);
  red[tid] = sm; __syncthreads();
  for (int s=128;s>0;s>>=1){ if (tid<s) red[tid] += red[tid+s]; __syncthreads(); }
  if (tid==0){ rowm[r] = m; rowinvl[r] = 1.0f/red[0]; }
}

// ---------------- Stage 4b: PV partials per k-tile ----------------------------------------------
__global__ __launch_bounds__(256) void k_pv(const float* __restrict__ Vg,
                                            const float* __restrict__ out1,
                                            const float* __restrict__ rowm, const float* __restrict__ rowinvl,
                                            float* __restrict__ pvpart){
  const int kt = blockIdx.x, b = blockIdx.y, tid = threadIdx.x;
  const int lane = tid & 63, w = tid >> 6;
  const int u0 = w*12;
  __shared__ float Vl[128][65];   // padded: lane-d reads conflict-free
  __shared__ float Pl[128][49];   // odd stride: lane-k writes conflict-free
  float acc[12];
  #pragma unroll
  for (int j=0;j<12;j++) acc[j] = 0.0f;
  for (int sc=0; sc<8; sc++){
    const int k0 = kt*KT5 + sc*128;
    {
      int r = tid >> 1, h = tid & 1;
      const float* vp = Vg + ((size_t)(b*LK + k0 + r))*DD + h*32;
      #pragma unroll
      for (int j=0;j<8;j++){
        float4 t = ((const float4*)vp)[j];
        Vl[r][h*32 + 4*j]   = t.x;
        Vl[r][h*32 + 4*j+1] = t.y;
        Vl[r][h*32 + 4*j+2] = t.z;
        Vl[r][h*32 + 4*j+3] = t.w;
      }
    }
    for (int e = tid; e < NU*128; e += 256){
      int u = e >> 7, kk = e & 127;
      int r = b*NU + u;
      float s = out1[((size_t)r<<15) + k0 + kk];
      Pl[kk][u] = __expf(s - rowm[r]) * rowinvl[r];
    }
    __syncthreads();
    for (int kk=0; kk<128; kk++){
      float v = Vl[kk][lane];
      #pragma unroll
      for (int j=0;j<12;j++){
        if (u0 + j < NU) acc[j] = fmaf(Pl[kk][u0+j], v, acc[j]);
      }
    }
    __syncthreads();
  }
  #pragma unroll
  for (int j=0;j<12;j++){
    if (u0 + j < NU){
      pvpart[(((size_t)(b*NU + u0 + j))*NT5 + kt)*DD + lane] = acc[j];
    }
  }
}

// ---------------- Stage 5: reduce PV partials -> output 0 ---------------------------------------
__global__ __launch_bounds__(256) void k_final(const float* __restrict__ pvpart, float* __restrict__ out0){
  int e = blockIdx.x*256 + threadIdx.x;
  if (e >= BB*NU*DD) return;
  int d = e & 63; int r = e >> 6;
  float s = 0.0f;
  for (int t=0;t<NT5;t++) s += pvpart[((size_t)r*NT5 + t)*DD + d];
  out0[e] = s;
}

extern "C" void kernel_launch(void* const* d_in, const int* in_sizes, int n_in,
                              void* d_out, int out_size, void* d_ws, size_t ws_size,
                              hipStream_t stream){
  const float* q  = (const float*)d_in[0];
  const float* K  = (const float*)d_in[1];
  const float* V  = (const float*)d_in[2];
  const int* idx  = (const int*)d_in[3];
  float* out0 = (float*)d_out;                 // attn_output: 8*45*64
  float* out1 = out0 + BB*NU*DD;               // attn_scores: 8*45*32768

  float* ws      = (float*)d_ws;
  float* Mpmax   = ws;                         // 8*4096*16 = 524288
  float* Mpsum   = Mpmax + (size_t)BB*LQ*NPH;  // 524288
  float* Qred    = Mpsum + (size_t)BB*LQ*NPH;  // 8*45*64 = 23040
  float* rowm    = Qred + (size_t)BB*NU*DD;    // 360 (pad 512)
  float* rowinvl = rowm + 512;                 // 360 (pad 512)
  float* pvpart  = rowinvl + 512;              // 8*45*32*64 = 737280
  int*   Mtop    = (int*)(pvpart + (size_t)BB*NU*NT5*DD);   // 360 ints

  k_M<<<dim3(NPH, LQ/64, BB), 64, 0, stream>>>(q, K, idx, Mpmax, Mpsum);
  k_select<<<BB, 256, 0, stream>>>(Mpmax, Mpsum, q, Mtop, Qred);
  k_scores<<<dim3(LK/256, BB), 256, 0, stream>>>(K, Qred, out1);
  k_rowstats<<<BB*NU, 256, 0, stream>>>(out1, rowm, rowinvl);
  k_pv<<<dim3(NT5, BB), 256, 0, stream>>>(V, out1, rowm, rowinvl, pvpart);
  k_final<<<(BB*NU*DD + 255)/256, 256, 0, stream>>>(pvpart, out0);
}

// Round 3
// 1274.191 us; speedup vs baseline: 1.3258x; 1.3258x over previous
//
#include <hip/hip_runtime.h>

#define BB 8
#define LQ 4096
#define LK 32768
#define DD 64
#define UU 8000
#define NU 45
#define NPH 20
#define UCH (UU/NPH)   // 400 u per phase, multiple of 4
#define KT5 1024
#define NT5 32

__device__ __forceinline__ unsigned int fkey(float v){
  unsigned int u = __float_as_uint(v);
  return (u & 0x80000000u) ? ~u : (u | 0x80000000u);
}

__device__ __forceinline__ float dot64(const float* __restrict__ qv, const float* __restrict__ kp){
  float a0=0.f,a1=0.f,a2=0.f,a3=0.f;
  #pragma unroll
  for (int j=0;j<64;j+=4){
    a0 = fmaf(qv[j],   kp[j],   a0);
    a1 = fmaf(qv[j+1], kp[j+1], a1);
    a2 = fmaf(qv[j+2], kp[j+2], a2);
    a3 = fmaf(qv[j+3], kp[j+3], a3);
  }
  return (a0+a1)+(a2+a3);
}

// ---------------- Stage 1: M partials. 4 waves/block (one phase each), contiguous u chunks, ----
// ---------------- int4 idx prefetch + 4 independent dots per iteration for ILP. ----------------
__global__ __launch_bounds__(256,4) void k_M(const float* __restrict__ q,
                                             const float* __restrict__ Kg,
                                             const int* __restrict__ idx,
                                             float* __restrict__ Mpmax, float* __restrict__ Mpsum){
  const int w = __builtin_amdgcn_readfirstlane(threadIdx.x >> 6);
  const int lane = threadIdx.x & 63;
  const int ph = blockIdx.x*4 + w;              // 0..19
  const int qt = blockIdx.y, b = blockIdx.z;
  const int qrow = qt*64 + lane;
  const float* qp = q + ((size_t)(b*LQ + qrow))*DD;
  float qv[64];
  #pragma unroll
  for (int j=0;j<16;j++){
    float4 t = ((const float4*)qp)[j];
    qv[4*j]=t.x; qv[4*j+1]=t.y; qv[4*j+2]=t.z; qv[4*j+3]=t.w;
  }
  const int u0 = ph*UCH, u1 = u0 + UCH;
  float vmax = -INFINITY, vsum = 0.0f;
  for (int u = u0; u < u1; u += 4){
    const int4 iv = *reinterpret_cast<const int4*>(idx + u);   // wave-uniform -> s_load_dwordx4
    const float* kp0 = Kg + ((size_t)(b*LK + iv.x))*DD;
    const float* kp1 = Kg + ((size_t)(b*LK + iv.y))*DD;
    const float* kp2 = Kg + ((size_t)(b*LK + iv.z))*DD;
    const float* kp3 = Kg + ((size_t)(b*LK + iv.w))*DD;
    float s0 = dot64(qv, kp0);
    float s1 = dot64(qv, kp1);
    float s2 = dot64(qv, kp2);
    float s3 = dot64(qv, kp3);
    vmax = fmaxf(vmax, fmaxf(fmaxf(s0,s1), fmaxf(s2,s3)));
    vsum += (s0+s1)+(s2+s3);
  }
  size_t o = ((size_t)(b*LQ + qrow))*NPH + ph;
  Mpmax[o] = vmax; Mpsum[o] = vsum;
}

// ---------------- Stage 2: per-batch stable bottom-45 of M (matches jax.lax.top_k(-M, 45)) ------
__global__ __launch_bounds__(256) void k_select(const float* __restrict__ Mpmax, const float* __restrict__ Mpsum,
                                                const float* __restrict__ q,
                                                int* __restrict__ MtopG, float* __restrict__ Qred){
  const int b = blockIdx.x, tid = threadIdx.x;
  __shared__ float Mv[LQ];
  __shared__ unsigned long long red[256];
  __shared__ int mtop[NU];
  for (int qq = tid; qq < LQ; qq += 256){
    size_t base = ((size_t)(b*LQ + qq))*NPH;
    float mx = -INFINITY, sm = 0.0f;
    #pragma unroll
    for (int p=0;p<NPH;p++){ mx = fmaxf(mx, Mpmax[base+p]); sm += Mpsum[base+p]; }
    Mv[qq] = mx - sm / 8000.0f;
  }
  __syncthreads();
  for (int i=0;i<NU;i++){
    unsigned long long best = ~0ull;
    for (int qq = tid; qq < LQ; qq += 256){
      unsigned long long kk = (((unsigned long long)fkey(Mv[qq]))<<32) | (unsigned int)qq;
      if (kk < best) best = kk;
    }
    red[tid] = best; __syncthreads();
    for (int s=128; s>0; s>>=1){
      if (tid < s && red[tid+s] < red[tid]) red[tid] = red[tid+s];
      __syncthreads();
    }
    int sel = (int)(red[0] & 0xFFFFFFFFull);
    __syncthreads();
    if (tid == 0){ Mv[sel] = INFINITY; mtop[i] = sel; }
    __syncthreads();
  }
  if (tid < NU) MtopG[b*NU + tid] = mtop[tid];
  for (int e = tid; e < NU*DD; e += 256){
    int ui = e >> 6, d = e & 63;
    Qred[((size_t)(b*NU + ui))*DD + d] = q[((size_t)(b*LQ + mtop[ui]))*DD + d];
  }
}

// ---------------- Stage 3: attn_scores (pre-softmax) -> output 1 --------------------------------
__global__ __launch_bounds__(256,4) void k_scores(const float* __restrict__ Kg,
                                                  const float* __restrict__ Qred,
                                                  float* __restrict__ out1){
  const int b = blockIdx.y;
  const int k = blockIdx.x*256 + threadIdx.x;
  const float* kp = Kg + ((size_t)(b*LK + k))*DD;
  float kv[64];
  #pragma unroll
  for (int j=0;j<16;j++){
    float4 t = ((const float4*)kp)[j];
    kv[4*j]=t.x; kv[4*j+1]=t.y; kv[4*j+2]=t.z; kv[4*j+3]=t.w;
  }
  for (int u=0; u<NU; u++){
    const float* qr = Qred + ((size_t)(b*NU+u))*DD;   // block-uniform -> scalar loads
    float s = dot64(kv, qr) * 0.125f;
    out1[((size_t)(b*NU+u)<<15) + k] = s;
  }
}

// ---------------- Stage 4a: softmax row stats ----------------------------------------------------
__global__ __launch_bounds__(256) void k_rowstats(const float* __restrict__ out1,
                                                  float* __restrict__ rowm, float* __restrict__ rowinvl){
  const int r = blockIdx.x, tid = threadIdx.x;
  const float* row = out1 + ((size_t)r << 15);
  __shared__ float red[256];
  float mx = -INFINITY;
  for (int k = tid; k < LK; k += 256) mx = fmaxf(mx, row[k]);
  red[tid] = mx; __syncthreads();
  for (int s=128;s>0;s>>=1){ if (tid<s) red[tid] = fmaxf(red[tid], red[tid+s]); __syncthreads(); }
  float m = red[0]; __syncthreads();
  float sm = 0.0f;
  for (int k = tid; k < LK; k += 256) sm += __expf(row[k] - m);
  red[tid] = sm; __syncthreads();
  for (int s=128;s>0;s>>=1){ if (tid<s) red[tid] += red[tid+s]; __syncthreads(); }
  if (tid==0){ rowm[r] = m; rowinvl[r] = 1.0f/red[0]; }
}

// ---------------- Stage 4b: PV partials per k-tile; P rows packed for b128 broadcast reads ------
__global__ __launch_bounds__(256) void k_pv(const float* __restrict__ Vg,
                                            const float* __restrict__ out1,
                                            const float* __restrict__ rowm, const float* __restrict__ rowinvl,
                                            float* __restrict__ pvpart){
  const int kt = blockIdx.x, b = blockIdx.y, tid = threadIdx.x;
  const int lane = tid & 63, w = tid >> 6;
  const int u0 = w*12;
  __shared__ float Vl[128][65];                  // lane-d reads conflict-free
  __shared__ __align__(16) float Pl[48][132];    // [u][k]: b128 broadcast reads; 16B-aligned rows
  float acc[12];
  #pragma unroll
  for (int j=0;j<12;j++) acc[j] = 0.0f;
  for (int sc=0; sc<8; sc++){
    const int k0 = kt*KT5 + sc*128;
    {
      int r = tid >> 1, h = tid & 1;
      const float* vp = Vg + ((size_t)(b*LK + k0 + r))*DD + h*32;
      #pragma unroll
      for (int j=0;j<8;j++){
        float4 t = ((const float4*)vp)[j];
        Vl[r][h*32 + 4*j]   = t.x;
        Vl[r][h*32 + 4*j+1] = t.y;
        Vl[r][h*32 + 4*j+2] = t.z;
        Vl[r][h*32 + 4*j+3] = t.w;
      }
    }
    for (int e = tid; e < 48*128; e += 256){
      int u = e >> 7, kk = e & 127;
      float p = 0.0f;
      if (u < NU){
        int r = b*NU + u;
        float s = out1[((size_t)r<<15) + k0 + kk];
        p = __expf(s - rowm[r]) * rowinvl[r];
      }
      Pl[u][kk] = p;
    }
    __syncthreads();
    for (int kk4=0; kk4<32; kk4++){
      float v0 = Vl[4*kk4+0][lane];
      float v1 = Vl[4*kk4+1][lane];
      float v2 = Vl[4*kk4+2][lane];
      float v3 = Vl[4*kk4+3][lane];
      #pragma unroll
      for (int j=0;j<12;j++){
        float4 p = *reinterpret_cast<const float4*>(&Pl[u0+j][4*kk4]);  // broadcast b128
        acc[j] = fmaf(p.w, v3, fmaf(p.z, v2, fmaf(p.y, v1, fmaf(p.x, v0, acc[j]))));
      }
    }
    __syncthreads();
  }
  #pragma unroll
  for (int j=0;j<12;j++){
    if (u0 + j < NU){
      pvpart[(((size_t)(b*NU + u0 + j))*NT5 + kt)*DD + lane] = acc[j];
    }
  }
}

// ---------------- Stage 5: reduce PV partials -> output 0 ---------------------------------------
__global__ __launch_bounds__(256) void k_final(const float* __restrict__ pvpart, float* __restrict__ out0){
  int e = blockIdx.x*256 + threadIdx.x;
  if (e >= BB*NU*DD) return;
  int d = e & 63; int r = e >> 6;
  float s = 0.0f;
  for (int t=0;t<NT5;t++) s += pvpart[((size_t)r*NT5 + t)*DD + d];
  out0[e] = s;
}

extern "C" void kernel_launch(void* const* d_in, const int* in_sizes, int n_in,
                              void* d_out, int out_size, void* d_ws, size_t ws_size,
                              hipStream_t stream){
  const float* q  = (const float*)d_in[0];
  const float* K  = (const float*)d_in[1];
  const float* V  = (const float*)d_in[2];
  const int* idx  = (const int*)d_in[3];
  float* out0 = (float*)d_out;                 // attn_output: 8*45*64
  float* out1 = out0 + BB*NU*DD;               // attn_scores: 8*45*32768

  // ws layout. pvpart aliases Mpmax/Mpsum (dead after k_select) to bound ws use at ~5.4 MB.
  float* ws      = (float*)d_ws;
  float* Mpmax   = ws;                               // 8*4096*20 = 655360
  float* Mpsum   = Mpmax + (size_t)BB*LQ*NPH;        // 655360
  float* pvpart  = ws;                               // 8*45*32*64 = 737280 (aliases Mp*)
  float* Qred    = Mpsum + (size_t)BB*LQ*NPH;        // 23040
  float* rowm    = Qred + (size_t)BB*NU*DD;          // pad 512
  float* rowinvl = rowm + 512;                       // pad 512
  int*   Mtop    = (int*)(rowinvl + 512);            // 360 ints

  k_M<<<dim3(NPH/4, LQ/64, BB), 256, 0, stream>>>(q, K, idx, Mpmax, Mpsum);
  k_select<<<BB, 256, 0, stream>>>(Mpmax, Mpsum, q, Mtop, Qred);
  k_scores<<<dim3(LK/256, BB), 256, 0, stream>>>(K, Qred, out1);
  k_rowstats<<<BB*NU, 256, 0, stream>>>(out1, rowm, rowinvl);
  k_pv<<<dim3(NT5, BB), 256, 0, stream>>>(V, out1, rowm, rowinvl, pvpart);
  k_final<<<(BB*NU*DD + 255)/256, 256, 0, stream>>>(pvpart, out0);
}

// Round 4
// 1016.591 us; speedup vs baseline: 1.6617x; 1.2534x over previous
//
#include <hip/hip_runtime.h>

#define BB 8
#define LQ 4096
#define LK 32768
#define DD 64
#define UU 8000
#define NU 45
#define TQ 64
#define TUC 160
#define NCH (UU/TUC)   // 50 chunks
#define KT5 1024
#define NT5 32

typedef short short8 __attribute__((ext_vector_type(8)));
typedef float floatx16 __attribute__((ext_vector_type(16)));

__device__ __forceinline__ float bf2f(unsigned short h){ return __uint_as_float(((unsigned int)h) << 16); }
__device__ __forceinline__ unsigned short f2bf(float f){
  unsigned int u = __float_as_uint(f);
  u += 0x7FFFu + ((u >> 16) & 1u);
  return (unsigned short)(u >> 16);
}
__device__ __forceinline__ unsigned int fkey(float v){
  unsigned int u = __float_as_uint(v);
  return (u & 0x80000000u) ? ~u : (u | 0x80000000u);
}
__device__ __forceinline__ float dot64(const float* __restrict__ a, const float* __restrict__ b){
  float a0=0.f,a1=0.f,a2=0.f,a3=0.f;
  #pragma unroll
  for (int j=0;j<64;j+=4){
    a0 = fmaf(a[j],   b[j],   a0);
    a1 = fmaf(a[j+1], b[j+1], a1);
    a2 = fmaf(a[j+2], b[j+2], a2);
    a3 = fmaf(a[j+3], b[j+3], a3);
  }
  return (a0+a1)+(a2+a3);
}

// ---------------- prep: gather K_samp rows, Dekker-split f32 -> bf16 hi+mid ---------------------
__global__ __launch_bounds__(256) void k_gather(const float* __restrict__ Kg, const int* __restrict__ idx,
                                                unsigned short* __restrict__ khi, unsigned short* __restrict__ kmid){
  const int b = blockIdx.y;
  const int row = blockIdx.x*32 + (threadIdx.x >> 3);
  const int oct = threadIdx.x & 7;
  const float* src = Kg + ((size_t)(b*LK + idx[row]))*DD + oct*8;
  float x[8];
  #pragma unroll
  for (int j=0;j<8;j++) x[j] = src[j];
  unsigned short h[8], m[8];
  #pragma unroll
  for (int j=0;j<8;j++){
    h[j] = f2bf(x[j]);
    m[j] = f2bf(x[j] - bf2f(h[j]));
  }
  size_t o = ((size_t)(b*UU + row))*DD + oct*8;
  #pragma unroll
  for (int j=0;j<8;j++){ khi[o+j]=h[j]; kmid[o+j]=m[j]; }
}

// partial sums of K_samp (for the exact mean term)
__global__ __launch_bounds__(64) void k_spart(const float* __restrict__ Kg, const int* __restrict__ idx,
                                              float* __restrict__ Spart){
  const int g = blockIdx.x, b = blockIdx.y, d = threadIdx.x;
  float acc = 0.0f;
  for (int j=0;j<64;j++){
    int u = g*64 + j;
    acc += Kg[((size_t)(b*LK + idx[u]))*DD + d];
  }
  Spart[((size_t)(b*125 + g))*DD + d] = acc;
}
__global__ __launch_bounds__(64) void k_sred(const float* __restrict__ Spart, float* __restrict__ Sb){
  const int b = blockIdx.x, d = threadIdx.x;
  float acc = 0.0f;
  for (int g=0; g<125; g++) acc += Spart[((size_t)(b*125 + g))*DD + d];
  Sb[b*DD + d] = acc;
}

// ---------------- Stage 1 (MFMA): approx max + arg-chunk per q ----------------------------------
// wave = one 32x32 C-tile-row; A (q hi/mid) in registers; B (K_samp hi/mid) LDS-staged per chunk.
__global__ __launch_bounds__(256,4) void k_Mm(const float* __restrict__ q,
                                              const unsigned short* __restrict__ khi,
                                              const unsigned short* __restrict__ kmid,
                                              float* __restrict__ amaxG, int* __restrict__ acargG){
  const int qt = blockIdx.x, b = blockIdx.y;
  const int tid = threadIdx.x;
  const int w = tid >> 6, lane = tid & 63;
  const int tr = w & 1, sp = w >> 1;
  const int l31 = lane & 31, lh = lane >> 5;
  __shared__ __align__(16) unsigned short Bh[TUC*DD];
  __shared__ __align__(16) unsigned short Bm[TUC*DD];
  __shared__ float combV[TQ][2];
  __shared__ int   combC[TQ][2];

  // A fragments: split q f32 -> bf16 hi/mid in-kernel. m = lane&31, k = s*16 + (lane>>5)*8 + j
  const int qrow = qt*TQ + tr*32 + l31;
  short8 ahi[4], amid[4];
  {
    const float* qp = q + ((size_t)(b*LQ) + qrow)*DD;
    #pragma unroll
    for (int s=0;s<4;s++){
      const int d0 = s*16 + lh*8;
      float4 x0 = *(const float4*)(qp + d0);
      float4 x1 = *(const float4*)(qp + d0 + 4);
      float xs[8] = {x0.x,x0.y,x0.z,x0.w,x1.x,x1.y,x1.z,x1.w};
      short8 h, m;
      #pragma unroll
      for (int j=0;j<8;j++){
        unsigned short hb = f2bf(xs[j]);
        unsigned short mb = f2bf(xs[j] - bf2f(hb));
        h[j] = (short)hb; m[j] = (short)mb;
      }
      ahi[s]=h; amid[s]=m;
    }
  }

  float vmax[16], snap[16]; int carg[16];
  #pragma unroll
  for (int r=0;r<16;r++){ vmax[r]=-INFINITY; snap[r]=-INFINITY; carg[r]=0; }

  const size_t kbyte = (size_t)b*UU*DD*2;   // byte base of this batch in khi/kmid
  for (int c=0;c<NCH;c++){
    __syncthreads();   // previous chunk's reads done before overwrite
    {
      const char* gh = (const char*)khi + kbyte + (size_t)c*TUC*DD*2;
      const char* gm = (const char*)kmid + kbyte + (size_t)c*TUC*DD*2;
      #pragma unroll
      for (int i=0;i<5;i++){
        int off = i*4096 + tid*16;
        *(uint4*)((char*)Bh + off) = *(const uint4*)(gh + off);
        *(uint4*)((char*)Bm + off) = *(const uint4*)(gm + off);
      }
    }
    __syncthreads();
    for (int t = sp; t < 5; t += 2){
      floatx16 acc = {0.f,0.f,0.f,0.f,0.f,0.f,0.f,0.f,0.f,0.f,0.f,0.f,0.f,0.f,0.f,0.f};
      #pragma unroll
      for (int s=0;s<4;s++){
        const int eo = (t*32 + l31)*DD + s*16 + lh*8;
        short8 bh = *(const short8*)(&Bh[eo]);
        short8 bm = *(const short8*)(&Bm[eo]);
        acc = __builtin_amdgcn_mfma_f32_32x32x16_bf16(amid[s], bh, acc, 0, 0, 0);
        acc = __builtin_amdgcn_mfma_f32_32x32x16_bf16(ahi[s],  bm, acc, 0, 0, 0);
        acc = __builtin_amdgcn_mfma_f32_32x32x16_bf16(ahi[s],  bh, acc, 0, 0, 0);
      }
      #pragma unroll
      for (int r=0;r<16;r++) vmax[r] = fmaxf(vmax[r], acc[r]);
    }
    #pragma unroll
    for (int r=0;r<16;r++){
      if (vmax[r] > snap[r]) carg[r] = c;
      snap[r] = vmax[r];
    }
  }
  // cross-lane reduce over the 32 u-columns (xor bits 0..4 only; lane>>5 selects rows)
  #pragma unroll
  for (int st=1; st<32; st<<=1){
    #pragma unroll
    for (int r=0;r<16;r++){
      float ov = __shfl_xor(vmax[r], st);
      int   oc = __shfl_xor(carg[r], st);
      if (ov > vmax[r]){ vmax[r]=ov; carg[r]=oc; }
    }
  }
  if (l31 == 0){
    #pragma unroll
    for (int r=0;r<16;r++){
      int m = (r&3) + 8*(r>>2) + 4*lh;
      int ql = tr*32 + m;
      combV[ql][sp] = vmax[r];
      combC[ql][sp] = carg[r];
    }
  }
  __syncthreads();
  if (tid < TQ){
    float v0 = combV[tid][0], v1 = combV[tid][1];
    int   c0 = combC[tid][0], c1 = combC[tid][1];
    bool t1 = v1 > v0;
    amaxG[(size_t)b*LQ + qt*TQ + tid] = t1 ? v1 : v0;
    acargG[(size_t)b*LQ + qt*TQ + tid] = t1 ? c1 : c0;
  }
}

// ---------------- refinement: exact f32 max within arg-chunk + exact mean -> M ------------------
__global__ __launch_bounds__(256) void k_ref(const float* __restrict__ q, const float* __restrict__ Kg,
                                             const int* __restrict__ idx, const float* __restrict__ Sb,
                                             const int* __restrict__ acargG, float* __restrict__ M){
  const int gq = blockIdx.x*256 + threadIdx.x;     // 0..32767
  const int b = gq >> 12, qr = gq & (LQ-1);
  const float* qp = q + ((size_t)b*LQ + qr)*DD;
  float qv[64];
  #pragma unroll
  for (int j=0;j<16;j++){
    float4 t = ((const float4*)qp)[j];
    qv[4*j]=t.x; qv[4*j+1]=t.y; qv[4*j+2]=t.z; qv[4*j+3]=t.w;
  }
  const int c = acargG[gq];
  float mx = -INFINITY;
  #pragma unroll 1
  for (int u = c*TUC; u < c*TUC + TUC; u++){
    const float* kp = Kg + ((size_t)(b*LK + idx[u]))*DD;
    mx = fmaxf(mx, dot64(qv, kp));
  }
  float mean = dot64(qv, Sb + b*DD) * (1.0f/8000.0f);
  M[gq] = mx - mean;
}

// ---------------- Stage 2: per-batch stable bottom-45 of M --------------------------------------
__global__ __launch_bounds__(256) void k_select(const float* __restrict__ Mg,
                                                const float* __restrict__ q,
                                                int* __restrict__ MtopG, float* __restrict__ Qred){
  const int b = blockIdx.x, tid = threadIdx.x;
  __shared__ float Mv[LQ];
  __shared__ unsigned long long red[256];
  __shared__ int mtop[NU];
  for (int qq = tid; qq < LQ; qq += 256) Mv[qq] = Mg[(size_t)b*LQ + qq];
  __syncthreads();
  for (int i=0;i<NU;i++){
    unsigned long long best = ~0ull;
    for (int qq = tid; qq < LQ; qq += 256){
      unsigned long long kk = (((unsigned long long)fkey(Mv[qq]))<<32) | (unsigned int)qq;
      if (kk < best) best = kk;
    }
    red[tid] = best; __syncthreads();
    for (int s=128; s>0; s>>=1){
      if (tid < s && red[tid+s] < red[tid]) red[tid] = red[tid+s];
      __syncthreads();
    }
    int sel = (int)(red[0] & 0xFFFFFFFFull);
    __syncthreads();
    if (tid == 0){ Mv[sel] = INFINITY; mtop[i] = sel; }
    __syncthreads();
  }
  if (tid < NU) MtopG[b*NU + tid] = mtop[tid];
  for (int e = tid; e < NU*DD; e += 256){
    int ui = e >> 6, d = e & 63;
    Qred[((size_t)(b*NU + ui))*DD + d] = q[((size_t)(b*LQ + mtop[ui]))*DD + d];
  }
}

// ---------------- Stage 3: attn_scores (pre-softmax) -> output 1 --------------------------------
__global__ __launch_bounds__(256,4) void k_scores(const float* __restrict__ Kg,
                                                  const float* __restrict__ Qred,
                                                  float* __restrict__ out1){
  const int b = blockIdx.y;
  const int k = blockIdx.x*256 + threadIdx.x;
  const float* kp = Kg + ((size_t)(b*LK + k))*DD;
  float kv[64];
  #pragma unroll
  for (int j=0;j<16;j++){
    float4 t = ((const float4*)kp)[j];
    kv[4*j]=t.x; kv[4*j+1]=t.y; kv[4*j+2]=t.z; kv[4*j+3]=t.w;
  }
  for (int u=0; u<NU; u++){
    const float* qr = Qred + ((size_t)(b*NU+u))*DD;   // block-uniform -> scalar loads
    float s = dot64(kv, qr) * 0.125f;
    out1[((size_t)(b*NU+u)<<15) + k] = s;
  }
}

// ---------------- Stage 4a: softmax row stats ---------------------------------------------------
__global__ __launch_bounds__(256) void k_rowstats(const float* __restrict__ out1,
                                                  float* __restrict__ rowm, float* __restrict__ rowinvl){
  const int r = blockIdx.x, tid = threadIdx.x;
  const float* row = out1 + ((size_t)r << 15);
  __shared__ float red[256];
  float mx = -INFINITY;
  for (int k = tid; k < LK; k += 256) mx = fmaxf(mx, row[k]);
  red[tid] = mx; __syncthreads();
  for (int s=128;s>0;s>>=1){ if (tid<s) red[tid] = fmaxf(red[tid], red[tid+s]); __syncthreads(); }
  float m = red[0]; __syncthreads();
  float sm = 0.0f;
  for (int k = tid; k < LK; k += 256) sm += __expf(row[k] - m);
  red[tid] = sm; __syncthreads();
  for (int s=128;s>0;s>>=1){ if (tid<s) red[tid] += red[tid+s]; __syncthreads(); }
  if (tid==0){ rowm[r] = m; rowinvl[r] = 1.0f/red[0]; }
}

// ---------------- Stage 4b: PV partials per k-tile ----------------------------------------------
__global__ __launch_bounds__(256) void k_pv(const float* __restrict__ Vg,
                                            const float* __restrict__ out1,
                                            const float* __restrict__ rowm, const float* __restrict__ rowinvl,
                                            float* __restrict__ pvpart){
  const int kt = blockIdx.x, b = blockIdx.y, tid = threadIdx.x;
  const int lane = tid & 63, w = tid >> 6;
  const int u0 = w*12;
  __shared__ float Vl[128][65];
  __shared__ __align__(16) float Pl[48][132];
  float acc[12];
  #pragma unroll
  for (int j=0;j<12;j++) acc[j] = 0.0f;
  for (int sc=0; sc<8; sc++){
    const int k0 = kt*KT5 + sc*128;
    {
      int r = tid >> 1, h = tid & 1;
      const float* vp = Vg + ((size_t)(b*LK + k0 + r))*DD + h*32;
      #pragma unroll
      for (int j=0;j<8;j++){
        float4 t = ((const float4*)vp)[j];
        Vl[r][h*32 + 4*j]   = t.x;
        Vl[r][h*32 + 4*j+1] = t.y;
        Vl[r][h*32 + 4*j+2] = t.z;
        Vl[r][h*32 + 4*j+3] = t.w;
      }
    }
    for (int e = tid; e < 48*128; e += 256){
      int u = e >> 7, kk = e & 127;
      float p = 0.0f;
      if (u < NU){
        int r = b*NU + u;
        float s = out1[((size_t)r<<15) + k0 + kk];
        p = __expf(s - rowm[r]) * rowinvl[r];
      }
      Pl[u][kk] = p;
    }
    __syncthreads();
    for (int kk4=0; kk4<32; kk4++){
      float v0 = Vl[4*kk4+0][lane];
      float v1 = Vl[4*kk4+1][lane];
      float v2 = Vl[4*kk4+2][lane];
      float v3 = Vl[4*kk4+3][lane];
      #pragma unroll
      for (int j=0;j<12;j++){
        float4 p = *reinterpret_cast<const float4*>(&Pl[u0+j][4*kk4]);
        acc[j] = fmaf(p.w, v3, fmaf(p.z, v2, fmaf(p.y, v1, fmaf(p.x, v0, acc[j]))));
      }
    }
    __syncthreads();
  }
  #pragma unroll
  for (int j=0;j<12;j++){
    if (u0 + j < NU){
      pvpart[(((size_t)(b*NU + u0 + j))*NT5 + kt)*DD + lane] = acc[j];
    }
  }
}

// ---------------- Stage 5: reduce PV partials -> output 0 ---------------------------------------
__global__ __launch_bounds__(256) void k_final(const float* __restrict__ pvpart, float* __restrict__ out0){
  int e = blockIdx.x*256 + threadIdx.x;
  if (e >= BB*NU*DD) return;
  int d = e & 63; int r = e >> 6;
  float s = 0.0f;
  for (int t=0;t<NT5;t++) s += pvpart[((size_t)r*NT5 + t)*DD + d];
  out0[e] = s;
}

extern "C" void kernel_launch(void* const* d_in, const int* in_sizes, int n_in,
                              void* d_out, int out_size, void* d_ws, size_t ws_size,
                              hipStream_t stream){
  const float* q  = (const float*)d_in[0];
  const float* K  = (const float*)d_in[1];
  const float* V  = (const float*)d_in[2];
  const int* idx  = (const int*)d_in[3];
  float* out0 = (float*)d_out;
  float* out1 = out0 + BB*NU*DD;

  float* ws = (float*)d_ws;
  // khi region also hosts pvpart later (khi dead after k_Mm; k_ref uses original K)
  unsigned short* khi  = (unsigned short*)ws;                        // 8*8000*64 bf16 = 8.192 MB
  float*  pvpart = ws;                                               // 737280 f32 (aliases khi)
  unsigned short* kmid = (unsigned short*)(ws + (size_t)BB*UU*DD/2); // 8.192 MB
  float* Spart   = ws + (size_t)BB*UU*DD;                            // 8*125*64 = 64000
  float* Sb      = Spart + 64000;                                    // 512
  float* amax    = Sb + 512;                                         // 32768
  int*   acarg   = (int*)(amax + BB*LQ);                             // 32768
  float* Mbq     = (float*)(acarg + BB*LQ);                          // 32768
  float* Qred    = Mbq + BB*LQ;                                      // 23040
  float* rowm    = Qred + (size_t)BB*NU*DD;                          // 512
  float* rowinvl = rowm + 512;                                       // 512
  int*   Mtop    = (int*)(rowinvl + 512);                            // 360

  k_gather<<<dim3(UU/32, BB), 256, 0, stream>>>(K, idx, khi, kmid);
  k_spart<<<dim3(125, BB), 64, 0, stream>>>(K, idx, Spart);
  k_sred<<<BB, 64, 0, stream>>>(Spart, Sb);
  k_Mm<<<dim3(LQ/TQ, BB), 256, 0, stream>>>(q, khi, kmid, amax, acarg);
  k_ref<<<BB*LQ/256, 256, 0, stream>>>(q, K, idx, Sb, acarg, Mbq);
  k_select<<<BB, 256, 0, stream>>>(Mbq, q, Mtop, Qred);
  k_scores<<<dim3(LK/256, BB), 256, 0, stream>>>(K, Qred, out1);
  k_rowstats<<<BB*NU, 256, 0, stream>>>(out1, rowm, rowinvl);
  k_pv<<<dim3(NT5, BB), 256, 0, stream>>>(V, out1, rowm, rowinvl, pvpart);
  k_final<<<(BB*NU*DD + 255)/256, 256, 0, stream>>>(pvpart, out0);
}

// Round 5
// 877.932 us; speedup vs baseline: 1.9242x; 1.1579x over previous
//
#include <hip/hip_runtime.h>

#define BB 8
#define LQ 4096
#define LK 32768
#define DD 64
#define UU 8000
#define NU 45
#define TQ 64
#define TUC 160
#define NCH (UU/TUC)   // 50 chunks
#define KT5 1024
#define NT5 32

typedef short short8 __attribute__((ext_vector_type(8)));
typedef float floatx16 __attribute__((ext_vector_type(16)));

__device__ __forceinline__ float bf2f(unsigned short h){ return __uint_as_float(((unsigned int)h) << 16); }
__device__ __forceinline__ unsigned short f2bf(float f){
  unsigned int u = __float_as_uint(f);
  u += 0x7FFFu + ((u >> 16) & 1u);
  return (unsigned short)(u >> 16);
}
__device__ __forceinline__ unsigned int fkey(float v){
  unsigned int u = __float_as_uint(v);
  return (u & 0x80000000u) ? ~u : (u | 0x80000000u);
}
__device__ __forceinline__ float dot64(const float* __restrict__ a, const float* __restrict__ b){
  float a0=0.f,a1=0.f,a2=0.f,a3=0.f;
  #pragma unroll
  for (int j=0;j<64;j+=4){
    a0 = fmaf(a[j],   b[j],   a0);
    a1 = fmaf(a[j+1], b[j+1], a1);
    a2 = fmaf(a[j+2], b[j+2], a2);
    a3 = fmaf(a[j+3], b[j+3], a3);
  }
  return (a0+a1)+(a2+a3);
}

// ---------------- prep: gather K_samp rows, Dekker-split f32 -> bf16 hi+mid ---------------------
__global__ __launch_bounds__(256) void k_gather(const float* __restrict__ Kg, const int* __restrict__ idx,
                                                unsigned short* __restrict__ khi, unsigned short* __restrict__ kmid){
  const int b = blockIdx.y;
  const int row = blockIdx.x*32 + (threadIdx.x >> 3);
  const int oct = threadIdx.x & 7;
  const float* src = Kg + ((size_t)(b*LK + idx[row]))*DD + oct*8;
  float x[8];
  #pragma unroll
  for (int j=0;j<8;j++) x[j] = src[j];
  unsigned short h[8], m[8];
  #pragma unroll
  for (int j=0;j<8;j++){
    h[j] = f2bf(x[j]);
    m[j] = f2bf(x[j] - bf2f(h[j]));
  }
  size_t o = ((size_t)(b*UU + row))*DD + oct*8;
  #pragma unroll
  for (int j=0;j<8;j++){ khi[o+j]=h[j]; kmid[o+j]=m[j]; }
}

// partial sums of K_samp (for the exact mean term)
__global__ __launch_bounds__(64) void k_spart(const float* __restrict__ Kg, const int* __restrict__ idx,
                                              float* __restrict__ Spart){
  const int g = blockIdx.x, b = blockIdx.y, d = threadIdx.x;
  float acc = 0.0f;
  for (int j=0;j<64;j++){
    int u = g*64 + j;
    acc += Kg[((size_t)(b*LK + idx[u]))*DD + d];
  }
  Spart[((size_t)(b*125 + g))*DD + d] = acc;
}
__global__ __launch_bounds__(64) void k_sred(const float* __restrict__ Spart, float* __restrict__ Sb){
  const int b = blockIdx.x, d = threadIdx.x;
  float acc = 0.0f;
  for (int g=0; g<125; g++) acc += Spart[((size_t)(b*125 + g))*DD + d];
  Sb[b*DD + d] = acc;
}

// ---------------- Stage 1 (MFMA): approx max + arg-chunk per q ----------------------------------
__global__ __launch_bounds__(256,4) void k_Mm(const float* __restrict__ q,
                                              const unsigned short* __restrict__ khi,
                                              const unsigned short* __restrict__ kmid,
                                              float* __restrict__ amaxG, int* __restrict__ acargG){
  const int qt = blockIdx.x, b = blockIdx.y;
  const int tid = threadIdx.x;
  const int w = tid >> 6, lane = tid & 63;
  const int tr = w & 1, sp = w >> 1;
  const int l31 = lane & 31, lh = lane >> 5;
  __shared__ __align__(16) unsigned short Bh[TUC*DD];
  __shared__ __align__(16) unsigned short Bm[TUC*DD];
  __shared__ float combV[TQ][2];
  __shared__ int   combC[TQ][2];

  const int qrow = qt*TQ + tr*32 + l31;
  short8 ahi[4], amid[4];
  {
    const float* qp = q + ((size_t)(b*LQ) + qrow)*DD;
    #pragma unroll
    for (int s=0;s<4;s++){
      const int d0 = s*16 + lh*8;
      float4 x0 = *(const float4*)(qp + d0);
      float4 x1 = *(const float4*)(qp + d0 + 4);
      float xs[8] = {x0.x,x0.y,x0.z,x0.w,x1.x,x1.y,x1.z,x1.w};
      short8 h, m;
      #pragma unroll
      for (int j=0;j<8;j++){
        unsigned short hb = f2bf(xs[j]);
        unsigned short mb = f2bf(xs[j] - bf2f(hb));
        h[j] = (short)hb; m[j] = (short)mb;
      }
      ahi[s]=h; amid[s]=m;
    }
  }

  float vmax[16], snap[16]; int carg[16];
  #pragma unroll
  for (int r=0;r<16;r++){ vmax[r]=-INFINITY; snap[r]=-INFINITY; carg[r]=0; }

  const size_t kbyte = (size_t)b*UU*DD*2;
  for (int c=0;c<NCH;c++){
    __syncthreads();
    {
      const char* gh = (const char*)khi + kbyte + (size_t)c*TUC*DD*2;
      const char* gm = (const char*)kmid + kbyte + (size_t)c*TUC*DD*2;
      #pragma unroll
      for (int i=0;i<5;i++){
        int off = i*4096 + tid*16;
        *(uint4*)((char*)Bh + off) = *(const uint4*)(gh + off);
        *(uint4*)((char*)Bm + off) = *(const uint4*)(gm + off);
      }
    }
    __syncthreads();
    for (int t = sp; t < 5; t += 2){
      floatx16 acc = {0.f,0.f,0.f,0.f,0.f,0.f,0.f,0.f,0.f,0.f,0.f,0.f,0.f,0.f,0.f,0.f};
      #pragma unroll
      for (int s=0;s<4;s++){
        const int eo = (t*32 + l31)*DD + s*16 + lh*8;
        short8 bh = *(const short8*)(&Bh[eo]);
        short8 bm = *(const short8*)(&Bm[eo]);
        acc = __builtin_amdgcn_mfma_f32_32x32x16_bf16(amid[s], bh, acc, 0, 0, 0);
        acc = __builtin_amdgcn_mfma_f32_32x32x16_bf16(ahi[s],  bm, acc, 0, 0, 0);
        acc = __builtin_amdgcn_mfma_f32_32x32x16_bf16(ahi[s],  bh, acc, 0, 0, 0);
      }
      #pragma unroll
      for (int r=0;r<16;r++) vmax[r] = fmaxf(vmax[r], acc[r]);
    }
    #pragma unroll
    for (int r=0;r<16;r++){
      if (vmax[r] > snap[r]) carg[r] = c;
      snap[r] = vmax[r];
    }
  }
  #pragma unroll
  for (int st=1; st<32; st<<=1){
    #pragma unroll
    for (int r=0;r<16;r++){
      float ov = __shfl_xor(vmax[r], st);
      int   oc = __shfl_xor(carg[r], st);
      if (ov > vmax[r]){ vmax[r]=ov; carg[r]=oc; }
    }
  }
  if (l31 == 0){
    #pragma unroll
    for (int r=0;r<16;r++){
      int m = (r&3) + 8*(r>>2) + 4*lh;
      int ql = tr*32 + m;
      combV[ql][sp] = vmax[r];
      combC[ql][sp] = carg[r];
    }
  }
  __syncthreads();
  if (tid < TQ){
    float v0 = combV[tid][0], v1 = combV[tid][1];
    int   c0 = combC[tid][0], c1 = combC[tid][1];
    bool t1 = v1 > v0;
    amaxG[(size_t)b*LQ + qt*TQ + tid] = t1 ? v1 : v0;
    acargG[(size_t)b*LQ + qt*TQ + tid] = t1 ? c1 : c0;
  }
}

// ---------------- refinement: one WAVE per q row; lanes split the 160-u chunk -------------------
__global__ __launch_bounds__(256) void k_ref(const float* __restrict__ q, const float* __restrict__ Kg,
                                             const int* __restrict__ idx, const float* __restrict__ Sb,
                                             const int* __restrict__ acargG, float* __restrict__ M){
  const int w = threadIdx.x >> 6, lane = threadIdx.x & 63;
  const int gq = blockIdx.x*4 + w;                 // 0..32767
  const int b = gq >> 12;
  const float* qp = q + (size_t)gq*DD;
  float qv[64];
  #pragma unroll
  for (int j=0;j<16;j++){
    float4 t = ((const float4*)qp)[j];
    qv[4*j]=t.x; qv[4*j+1]=t.y; qv[4*j+2]=t.z; qv[4*j+3]=t.w;
  }
  const int base = acargG[gq]*TUC;                 // wave-uniform
  float mx = -INFINITY;
  #pragma unroll
  for (int i=0;i<3;i++){
    int ul = i*64 + lane;
    if (ul < TUC){
      const float* kp = Kg + ((size_t)(b*LK + idx[base + ul]))*DD;
      mx = fmaxf(mx, dot64(qv, kp));
    }
  }
  #pragma unroll
  for (int st=1; st<64; st<<=1) mx = fmaxf(mx, __shfl_xor(mx, st));
  if (lane == 0){
    float mean = dot64(qv, Sb + b*DD) * (1.0f/8000.0f);
    M[gq] = mx - mean;
  }
}

// ---------------- Stage 2: per-batch stable bottom-45 of M (cached local-min argmin) ------------
__global__ __launch_bounds__(256) void k_select(const float* __restrict__ Mg,
                                                const float* __restrict__ q,
                                                int* __restrict__ MtopG, float* __restrict__ Qred){
  const int b = blockIdx.x, tid = threadIdx.x;
  __shared__ float Mv[LQ];
  __shared__ unsigned long long wmin[4];
  __shared__ int mtop[NU];
  __shared__ int selB;
  for (int qq = tid; qq < LQ; qq += 256) Mv[qq] = Mg[(size_t)b*LQ + qq];
  __syncthreads();
  unsigned long long lm = ~0ull;
  #pragma unroll
  for (int i=0;i<16;i++){
    int qq = tid + 256*i;
    unsigned long long kk = (((unsigned long long)fkey(Mv[qq]))<<32) | (unsigned int)qq;
    lm = (kk < lm) ? kk : lm;
  }
  for (int i=0;i<NU;i++){
    unsigned long long v = lm;
    #pragma unroll
    for (int st=1; st<64; st<<=1){
      unsigned long long o = __shfl_xor(v, st);
      v = (o < v) ? o : v;
    }
    if ((tid & 63) == 0) wmin[tid>>6] = v;
    __syncthreads();
    if (tid == 0){
      unsigned long long g01 = (wmin[0] < wmin[1]) ? wmin[0] : wmin[1];
      unsigned long long g23 = (wmin[2] < wmin[3]) ? wmin[2] : wmin[3];
      unsigned long long g = (g01 < g23) ? g01 : g23;
      int sel = (int)(g & 0xFFFFFFFFull);
      mtop[i] = sel; selB = sel; Mv[sel] = INFINITY;
    }
    __syncthreads();
    int sel = selB;
    if (tid == (sel & 255)){
      unsigned long long nl = ~0ull;
      #pragma unroll
      for (int j=0;j<16;j++){
        int qq = tid + 256*j;
        unsigned long long kk = (((unsigned long long)fkey(Mv[qq]))<<32) | (unsigned int)qq;
        nl = (kk < nl) ? kk : nl;
      }
      lm = nl;
    }
    __syncthreads();
  }
  if (tid < NU) MtopG[b*NU + tid] = mtop[tid];
  for (int e = tid; e < NU*DD; e += 256){
    int ui = e >> 6, d = e & 63;
    Qred[((size_t)(b*NU + ui))*DD + d] = q[((size_t)(b*LQ + mtop[ui]))*DD + d];
  }
}

// ---------------- Stage 3: attn_scores (pre-softmax) -> output 1 --------------------------------
__global__ __launch_bounds__(256,4) void k_scores(const float* __restrict__ Kg,
                                                  const float* __restrict__ Qred,
                                                  float* __restrict__ out1){
  const int b = blockIdx.y;
  const int k = blockIdx.x*256 + threadIdx.x;
  const float* kp = Kg + ((size_t)(b*LK + k))*DD;
  float kv[64];
  #pragma unroll
  for (int j=0;j<16;j++){
    float4 t = ((const float4*)kp)[j];
    kv[4*j]=t.x; kv[4*j+1]=t.y; kv[4*j+2]=t.z; kv[4*j+3]=t.w;
  }
  for (int u=0; u<NU; u++){
    const float* qr = Qred + ((size_t)(b*NU+u))*DD;
    float s = dot64(kv, qr) * 0.125f;
    out1[((size_t)(b*NU+u)<<15) + k] = s;
  }
}

// ---------------- Stage 4a: softmax row stats ---------------------------------------------------
__global__ __launch_bounds__(256) void k_rowstats(const float* __restrict__ out1,
                                                  float* __restrict__ rowm, float* __restrict__ rowinvl){
  const int r = blockIdx.x, tid = threadIdx.x;
  const float* row = out1 + ((size_t)r << 15);
  __shared__ float red[256];
  float mx = -INFINITY;
  for (int k = tid; k < LK; k += 256) mx = fmaxf(mx, row[k]);
  red[tid] = mx; __syncthreads();
  for (int s=128;s>0;s>>=1){ if (tid<s) red[tid] = fmaxf(red[tid], red[tid+s]); __syncthreads(); }
  float m = red[0]; __syncthreads();
  float sm = 0.0f;
  for (int k = tid; k < LK; k += 256) sm += __expf(row[k] - m);
  red[tid] = sm; __syncthreads();
  for (int s=128;s>0;s>>=1){ if (tid<s) red[tid] += red[tid+s]; __syncthreads(); }
  if (tid==0){ rowm[r] = m; rowinvl[r] = 1.0f/red[0]; }
}

// ---------------- Stage 4b: PV partials per k-tile ----------------------------------------------
__global__ __launch_bounds__(256) void k_pv(const float* __restrict__ Vg,
                                            const float* __restrict__ out1,
                                            const float* __restrict__ rowm, const float* __restrict__ rowinvl,
                                            float* __restrict__ pvpart){
  const int kt = blockIdx.x, b = blockIdx.y, tid = threadIdx.x;
  const int lane = tid & 63, w = tid >> 6;
  const int u0 = w*12;
  __shared__ float Vl[128][65];
  __shared__ __align__(16) float Pl[48][132];
  float acc[12];
  #pragma unroll
  for (int j=0;j<12;j++) acc[j] = 0.0f;
  for (int sc=0; sc<8; sc++){
    const int k0 = kt*KT5 + sc*128;
    {
      int r = tid >> 1, h = tid & 1;
      const float* vp = Vg + ((size_t)(b*LK + k0 + r))*DD + h*32;
      #pragma unroll
      for (int j=0;j<8;j++){
        float4 t = ((const float4*)vp)[j];
        Vl[r][h*32 + 4*j]   = t.x;
        Vl[r][h*32 + 4*j+1] = t.y;
        Vl[r][h*32 + 4*j+2] = t.z;
        Vl[r][h*32 + 4*j+3] = t.w;
      }
    }
    for (int e = tid; e < 48*128; e += 256){
      int u = e >> 7, kk = e & 127;
      float p = 0.0f;
      if (u < NU){
        int r = b*NU + u;
        float s = out1[((size_t)r<<15) + k0 + kk];
        p = __expf(s - rowm[r]) * rowinvl[r];
      }
      Pl[u][kk] = p;
    }
    __syncthreads();
    for (int kk4=0; kk4<32; kk4++){
      float v0 = Vl[4*kk4+0][lane];
      float v1 = Vl[4*kk4+1][lane];
      float v2 = Vl[4*kk4+2][lane];
      float v3 = Vl[4*kk4+3][lane];
      #pragma unroll
      for (int j=0;j<12;j++){
        float4 p = *reinterpret_cast<const float4*>(&Pl[u0+j][4*kk4]);
        acc[j] = fmaf(p.w, v3, fmaf(p.z, v2, fmaf(p.y, v1, fmaf(p.x, v0, acc[j]))));
      }
    }
    __syncthreads();
  }
  #pragma unroll
  for (int j=0;j<12;j++){
    if (u0 + j < NU){
      pvpart[(((size_t)(b*NU + u0 + j))*NT5 + kt)*DD + lane] = acc[j];
    }
  }
}

// ---------------- Stage 5: reduce PV partials -> output 0 ---------------------------------------
__global__ __launch_bounds__(256) void k_final(const float* __restrict__ pvpart, float* __restrict__ out0){
  int e = blockIdx.x*256 + threadIdx.x;
  if (e >= BB*NU*DD) return;
  int d = e & 63; int r = e >> 6;
  float s = 0.0f;
  for (int t=0;t<NT5;t++) s += pvpart[((size_t)r*NT5 + t)*DD + d];
  out0[e] = s;
}

extern "C" void kernel_launch(void* const* d_in, const int* in_sizes, int n_in,
                              void* d_out, int out_size, void* d_ws, size_t ws_size,
                              hipStream_t stream){
  const float* q  = (const float*)d_in[0];
  const float* K  = (const float*)d_in[1];
  const float* V  = (const float*)d_in[2];
  const int* idx  = (const int*)d_in[3];
  float* out0 = (float*)d_out;
  float* out1 = out0 + BB*NU*DD;

  float* ws = (float*)d_ws;
  unsigned short* khi  = (unsigned short*)ws;                        // 8*8000*64 bf16 = 8.192 MB
  float*  pvpart = ws;                                               // 737280 f32 (aliases khi; khi dead by k_pv)
  unsigned short* kmid = (unsigned short*)(ws + (size_t)BB*UU*DD/2); // 8.192 MB
  float* Spart   = ws + (size_t)BB*UU*DD;                            // 8*125*64 = 64000
  float* Sb      = Spart + 64000;                                    // 512
  float* amax    = Sb + 512;                                         // 32768
  int*   acarg   = (int*)(amax + BB*LQ);                             // 32768
  float* Mbq     = (float*)(acarg + BB*LQ);                          // 32768
  float* Qred    = Mbq + BB*LQ;                                      // 23040
  float* rowm    = Qred + (size_t)BB*NU*DD;                          // 512
  float* rowinvl = rowm + 512;                                       // 512
  int*   Mtop    = (int*)(rowinvl + 512);                            // 360

  k_gather<<<dim3(UU/32, BB), 256, 0, stream>>>(K, idx, khi, kmid);
  k_spart<<<dim3(125, BB), 64, 0, stream>>>(K, idx, Spart);
  k_sred<<<BB, 64, 0, stream>>>(Spart, Sb);
  k_Mm<<<dim3(LQ/TQ, BB), 256, 0, stream>>>(q, khi, kmid, amax, acarg);
  k_ref<<<BB*LQ/4, 256, 0, stream>>>(q, K, idx, Sb, acarg, Mbq);
  k_select<<<BB, 256, 0, stream>>>(Mbq, q, Mtop, Qred);
  k_scores<<<dim3(LK/256, BB), 256, 0, stream>>>(K, Qred, out1);
  k_rowstats<<<BB*NU, 256, 0, stream>>>(out1, rowm, rowinvl);
  k_pv<<<dim3(NT5, BB), 256, 0, stream>>>(V, out1, rowm, rowinvl, pvpart);
  k_final<<<(BB*NU*DD + 255)/256, 256, 0, stream>>>(pvpart, out0);
}